// Round 8
// baseline (336.554 us; speedup 1.0000x reference)
//
#include <hip/hip_runtime.h>

#define DEV __device__ __forceinline__

typedef __attribute__((ext_vector_type(8))) short short8v;
typedef __attribute__((ext_vector_type(4))) float f32x4;

DEV unsigned short f2bf(float f) {
  unsigned int x = __float_as_uint(f);
  x = x + 0x7FFFu + ((x >> 16) & 1u);   // RNE
  return (unsigned short)(x >> 16);
}
DEV float bf2f(unsigned short u) {
  return __uint_as_float(((unsigned)u) << 16);
}

// ---- swizzled LDS tile, BK=64: row stride 128 B, 8x16B chunks (0 confl) ----
DEV int swz_byte(int row, int kElem) {
  int chunk = ((kElem >> 3) ^ (row & 7));
  return row * 128 + (chunk << 4) + ((kElem & 7) << 1);
}

// Stage ROUNDS*32 rows x 64 cols of bf16 (256-thread kernels), BK=64 swizzle.
template <int ROUNDS>
DEV void stage(const unsigned short* __restrict__ g, int ld,
               unsigned short* tile, int tid) {
  const int wave = tid >> 6, l = tid & 63;
#pragma unroll
  for (int p = 0; p < ROUNDS; ++p) {
    const int r = (p << 5) + (wave << 3) + (l >> 3);
    const int c = ((l & 7) ^ (r & 7)) << 3;              // pre-swizzled col
    const unsigned short* src = g + (long)r * ld + c;
#if __has_builtin(__builtin_amdgcn_global_load_lds)
    unsigned short* dst = tile + (p << 11) + (wave << 9);  // wave-uniform
    __builtin_amdgcn_global_load_lds(
        (const __attribute__((address_space(1))) void*)src,
        (__attribute__((address_space(3))) void*)dst, 16, 0, 0);
#else
    short8v v = *reinterpret_cast<const short8v*>(src);
    *reinterpret_cast<short8v*>(reinterpret_cast<char*>(tile) +
                                (p << 12) + (wave << 10) + (l << 4)) = v;
#endif
  }
}

// NT GEMM, bf16 inputs: C[M][N] = A[M][K] * B[N][K]^T. Tile BM x 128, BK=64.
// EPI: 0 -> bf16; 1 -> f32; 2 -> masked raw scores BF16 + stats; 3 -> f32+stats
// GM (grid mode): 0: (x=nt, y=mt, z=z); 1: 1-D batch->XCD swizzle (scores);
//                 2: (x=mt, y=nt, z=z)  (panel co-location for single batch)
template <int BM, int EPI, int GM>
__global__ __launch_bounds__(256) void gemm_bf16(
    const unsigned short* __restrict__ A, const unsigned short* __restrict__ B,
    void* __restrict__ Cout, int M, int N, int K,
    long aBatch, long bBatch, long cBatch,
    const int* __restrict__ srcMask, const int* __restrict__ melMask,
    float scale, float* __restrict__ stats) {
  constexpr int NI = BM / 32;
  __shared__ unsigned short As[BM * 64];
  __shared__ unsigned short Bs[128 * 64];
  const int tid = threadIdx.x;
  const int lane = tid & 63;
  const int wave = tid >> 6;
  int z, bmi, bni;
  if constexpr (GM == 1) {
    const int id = blockIdx.x;            // 16z x 16nt x 8mt = 2048
    z = (id & 7) | ((id >> 10) << 3);
    const int ib = (id >> 3) & 127;
    bni = ib & 15;
    bmi = ib >> 4;
  } else if constexpr (GM == 2) {
    bmi = blockIdx.x; bni = blockIdx.y; z = blockIdx.z;
  } else {
    bni = blockIdx.x; bmi = blockIdx.y; z = blockIdx.z;
  }
  const int bm = bmi * BM;
  const int bn = bni * 128;
  const unsigned short* Ab = A + (long)z * aBatch;
  const unsigned short* Bb = B + (long)z * bBatch;
  const long cOff = (long)z * cBatch;
  const int wr = (wave >> 1) * (BM / 2);
  const int wc = (wave & 1) * 64;
  const int l15 = lane & 15;
  const int lHi = lane >> 4;

  f32x4 acc[NI][4] = {};

  for (int kt = 0; kt < K; kt += 64) {
    stage<BM / 32>(Ab + (long)bm * K + kt, K, As, tid);
    stage<4>(Bb + (long)bn * K + kt, K, Bs, tid);
    __syncthreads();
#pragma unroll
    for (int ks = 0; ks < 2; ++ks) {
      const int k0 = (ks << 5) + (lHi << 3);
      short8v af[NI], bfr[4];
#pragma unroll
      for (int i = 0; i < NI; ++i)
        af[i] = *reinterpret_cast<const short8v*>(
            reinterpret_cast<const char*>(As) + swz_byte(wr + i * 16 + l15, k0));
#pragma unroll
      for (int j = 0; j < 4; ++j)
        bfr[j] = *reinterpret_cast<const short8v*>(
            reinterpret_cast<const char*>(Bs) + swz_byte(wc + j * 16 + l15, k0));
#pragma unroll
      for (int i = 0; i < NI; ++i)
#pragma unroll
        for (int j = 0; j < 4; ++j)
          acc[i][j] = __builtin_amdgcn_mfma_f32_16x16x32_bf16(af[i], bfr[j], acc[i][j], 0, 0, 0);
    }
    __syncthreads();
  }

  if constexpr (EPI >= 2) {
    __shared__ float redM[128][2];
    __shared__ float redS[128][2];
    const int wcIdx = wave & 1;
#pragma unroll
    for (int i = 0; i < NI; ++i) {
#pragma unroll
      for (int rr = 0; rr < 4; ++rr) {
        const int rloc = wr + i * 16 + lHi * 4 + rr;
        const int rb = bm + rloc;
        const bool sm = srcMask[z * 1024 + rb] != 0;
        float vals[4];
        float m_l = -3.0e38f;
#pragma unroll
        for (int j = 0; j < 4; ++j) {
          const int c = bn + wc + j * 16 + l15;
          const bool mm = melMask[z * 2048 + c] != 0;
          const float vf = (sm && mm) ? -1e30f : acc[i][j][rr] * scale;
          vals[j] = vf;
          if constexpr (EPI == 2)
            reinterpret_cast<unsigned short*>(Cout)[cOff + (long)rb * N + c] = f2bf(vf);
          else
            reinterpret_cast<float*>(Cout)[cOff + (long)rb * N + c] = vf;
          m_l = fmaxf(m_l, vf);
        }
        if (stats) {
#pragma unroll
          for (int o = 1; o < 16; o <<= 1) m_l = fmaxf(m_l, __shfl_xor(m_l, o, 64));
          float s_l = 0.f;
#pragma unroll
          for (int j = 0; j < 4; ++j) s_l += __expf(vals[j] - m_l);
#pragma unroll
          for (int o = 1; o < 16; o <<= 1) s_l += __shfl_xor(s_l, o, 64);
          if (l15 == 0) { redM[rloc][wcIdx] = m_l; redS[rloc][wcIdx] = s_l; }
        }
      }
    }
    if (stats) {
      __syncthreads();
      if (tid < 128) {
        const float m0 = redM[tid][0], m1 = redM[tid][1];
        const float Mx = fmaxf(m0, m1);
        const float S = redS[tid][0] * __expf(m0 - Mx) + redS[tid][1] * __expf(m1 - Mx);
        const long sidx = ((long)(z * 1024 + bm + tid)) * 32 + (long)bni * 2;
        stats[sidx] = Mx;
        stats[sidx + 1] = S;
      }
    }
  } else {
#pragma unroll
    for (int i = 0; i < NI; ++i) {
#pragma unroll
      for (int j = 0; j < 4; ++j) {
        const int rb = bm + wr + i * 16 + lHi * 4;
        const int c = bn + wc + j * 16 + l15;
#pragma unroll
        for (int r = 0; r < 4; ++r) {
          const float v = acc[i][j][r];
          const long idx = cOff + (long)(rb + r) * N + c;
          if constexpr (EPI == 0)
            reinterpret_cast<unsigned short*>(Cout)[idx] = f2bf(v);
          else
            reinterpret_cast<float*>(Cout)[idx] = v;
        }
      }
    }
  }
}

// Merged k+v projection: one pass over mel. Per block: 128 s-rows x 128 m-cols.
__global__ __launch_bounds__(256) void gemm_kv(
    const unsigned short* __restrict__ mel, const unsigned short* __restrict__ WkT,
    const unsigned short* __restrict__ WvT, unsigned short* __restrict__ kbf,
    unsigned short* __restrict__ vT) {
  __shared__ unsigned short Ms[128 * 64];
  __shared__ unsigned short Ks[128 * 64];
  __shared__ unsigned short Vs[128 * 64];
  const int id = blockIdx.x;                 // 16z x 16st x 4mt
  const int z = (id & 7) | ((id >> 9) << 3);
  const int ib = (id >> 3) & 63;
  const int st = ib & 15, mt = ib >> 4;
  const int bs = st * 128, bmm = mt * 128;
  const int tid = threadIdx.x, lane = tid & 63, wave = tid >> 6;
  const int wrS = (wave >> 1) * 64, wcM = (wave & 1) * 64;
  const int l15 = lane & 15, lHi = lane >> 4;
  const unsigned short* melB = mel + ((long)z * 2048 + bs) * 512;

  f32x4 ak[4][4] = {};
  f32x4 av[4][4] = {};

  for (int kt = 0; kt < 512; kt += 64) {
    stage<4>(melB + kt, 512, Ms, tid);
    stage<4>(WkT + (long)bmm * 512 + kt, 512, Ks, tid);
    stage<4>(WvT + (long)bmm * 512 + kt, 512, Vs, tid);
    __syncthreads();
#pragma unroll
    for (int ks = 0; ks < 2; ++ks) {
      const int k0 = (ks << 5) + (lHi << 3);
      short8v mf[4], wf[4];
#pragma unroll
      for (int i = 0; i < 4; ++i)
        mf[i] = *reinterpret_cast<const short8v*>(
            reinterpret_cast<const char*>(Ms) + swz_byte(wrS + i * 16 + l15, k0));
#pragma unroll
      for (int j = 0; j < 4; ++j)
        wf[j] = *reinterpret_cast<const short8v*>(
            reinterpret_cast<const char*>(Ks) + swz_byte(wcM + j * 16 + l15, k0));
#pragma unroll
      for (int i = 0; i < 4; ++i)
#pragma unroll
        for (int j = 0; j < 4; ++j)
          ak[i][j] = __builtin_amdgcn_mfma_f32_16x16x32_bf16(mf[i], wf[j], ak[i][j], 0, 0, 0);
#pragma unroll
      for (int j = 0; j < 4; ++j)
        wf[j] = *reinterpret_cast<const short8v*>(
            reinterpret_cast<const char*>(Vs) + swz_byte(wcM + j * 16 + l15, k0));
#pragma unroll
      for (int i = 0; i < 4; ++i)
#pragma unroll
        for (int j = 0; j < 4; ++j)
          av[j][i] = __builtin_amdgcn_mfma_f32_16x16x32_bf16(wf[j], mf[i], av[j][i], 0, 0, 0);
    }
    __syncthreads();
  }

#pragma unroll
  for (int i = 0; i < 4; ++i)
#pragma unroll
    for (int j = 0; j < 4; ++j) {
      const int srow = bs + wrS + i * 16 + lHi * 4;
      const int mcol = bmm + wcM + j * 16 + l15;
      const int mrow = bmm + wcM + j * 16 + lHi * 4;
      const int scol = bs + wrS + i * 16 + l15;
#pragma unroll
      for (int rr = 0; rr < 4; ++rr) {
        kbf[((long)z * 2048 + srow + rr) * 512 + mcol] = f2bf(ak[i][j][rr]);
        vT[((long)z * 512 + mrow + rr) * 2048 + scol] = f2bf(av[j][i][rr]);
      }
    }
}

// Fused softmax + PV, 2-phase single-barrier pipeline (T3-minimum).
// BM=64 q-rows x BN=128 out-cols, BK=64, 256 thr, dbuf As/Bs.
// Block nt writes normalized attn fp32 for kt in [nt*512,(nt+1)*512).
// 1-D grid 1024 (16z x 16mt x 4nt), batch->XCD co-located.
__global__ __launch_bounds__(256) void pv_smx(
    const unsigned short* __restrict__ sbf, const unsigned short* __restrict__ vT,
    float* __restrict__ attn, float* __restrict__ out,
    const float* __restrict__ stats) {
  __shared__ unsigned short As[2][64 * 64];    // 2 x 8 KB
  __shared__ unsigned short Bs[2][128 * 64];   // 2 x 16 KB
  __shared__ float rowM[64], rowInv[64];
  const int id = blockIdx.x;
  const int z = (id & 7) | ((id >> 9) << 3);
  const int ib = (id >> 3) & 63;
  const int mt = ib & 15, nt = ib >> 4;
  const int bm = mt * 64, bn = nt * 128;
  const int tid = threadIdx.x, lane = tid & 63, wave = tid >> 6;

  if (tid < 64) {
    const float* st = stats + ((long)(z * 1024 + bm + tid)) * 32;
    float Mx = -3.0e38f;
#pragma unroll
    for (int t = 0; t < 16; ++t) Mx = fmaxf(Mx, st[t * 2]);
    float S = 0.f;
#pragma unroll
    for (int t = 0; t < 16; ++t) S += st[t * 2 + 1] * __expf(st[t * 2] - Mx);
    rowM[tid] = Mx;
    rowInv[tid] = 1.0f / S;
  }
  __syncthreads();

  const int ar = tid >> 2;               // A row 0..63 (4 thr/row)
  const int ac = (tid & 3) << 4;         // 16 elems per thread
  const float mR = rowM[ar];
  const float invR = rowInv[ar];
  const long aOff = ((long)z * 1024 + bm + ar) * 2048 + ac;
  const unsigned short* vTb = vT + ((long)z * 512 + bn) * 2048;
  const int wr = (wave >> 1) * 32, wc = (wave & 1) * 64;
  const int l15 = lane & 15, lHi = lane >> 4;

  f32x4 acc[2][4] = {};
  short8v s0, s1;

  auto loadS = [&](int kt) {
    s0 = *reinterpret_cast<const short8v*>(sbf + aOff + kt);
    s1 = *reinterpret_cast<const short8v*>(sbf + aOff + kt + 8);
  };
  auto computeA = [&](int kt, unsigned short* AsB) {
    float e[16];
#pragma unroll
    for (int u = 0; u < 8; ++u) {
      e[u] = __expf(bf2f((unsigned short)s0[u]) - mR) * invR;
      e[u + 8] = __expf(bf2f((unsigned short)s1[u]) - mR) * invR;
    }
    if ((kt >> 9) == nt) {               // balanced exactly-once attn write
      float* ap = attn + aOff + kt;
#pragma unroll
      for (int g = 0; g < 4; ++g) {
        float4 w;
        w.x = e[g * 4]; w.y = e[g * 4 + 1]; w.z = e[g * 4 + 2]; w.w = e[g * 4 + 3];
        *reinterpret_cast<float4*>(ap + g * 4) = w;
      }
    }
    short8v pk0, pk1;
#pragma unroll
    for (int u = 0; u < 8; ++u) {
      pk0[u] = (short)f2bf(e[u]);
      pk1[u] = (short)f2bf(e[u + 8]);
    }
    *reinterpret_cast<short8v*>(reinterpret_cast<char*>(AsB) + swz_byte(ar, ac)) = pk0;
    *reinterpret_cast<short8v*>(reinterpret_cast<char*>(AsB) + swz_byte(ar, ac + 8)) = pk1;
  };

  // ---- prologue: tile 0 into buffer 0 ----
  stage<4>(vTb, 2048, Bs[0], tid);
  loadS(0);
  computeA(0, As[0]);
  asm volatile("s_waitcnt vmcnt(0) lgkmcnt(0)" ::: "memory");
  __builtin_amdgcn_s_barrier();
  __builtin_amdgcn_sched_barrier(0);

  // ---- main loop: one barrier per K-step ----
  for (int t = 0; t < 32; ++t) {
    const int c = t & 1;
    if (t < 31) {
      stage<4>(vTb + (t + 1) * 64, 2048, Bs[c ^ 1], tid);   // prefetch B(t+1)
      loadS((t + 1) * 64);                                   // prefetch sbf(t+1)
    }
    const unsigned short* AsC = As[c];
    const unsigned short* BsC = Bs[c];
#pragma unroll
    for (int ks = 0; ks < 2; ++ks) {
      const int k0 = (ks << 5) + (lHi << 3);
      short8v af[2], bfr[4];
#pragma unroll
      for (int i = 0; i < 2; ++i)
        af[i] = *reinterpret_cast<const short8v*>(
            reinterpret_cast<const char*>(AsC) + swz_byte(wr + i * 16 + l15, k0));
#pragma unroll
      for (int j = 0; j < 4; ++j)
        bfr[j] = *reinterpret_cast<const short8v*>(
            reinterpret_cast<const char*>(BsC) + swz_byte(wc + j * 16 + l15, k0));
#pragma unroll
      for (int i = 0; i < 2; ++i)
#pragma unroll
        for (int j = 0; j < 4; ++j)
          acc[i][j] = __builtin_amdgcn_mfma_f32_16x16x32_bf16(af[i], bfr[j], acc[i][j], 0, 0, 0);
    }
    if (t < 31) computeA((t + 1) * 64, As[c ^ 1]);          // exp under the drain
    asm volatile("s_waitcnt vmcnt(0) lgkmcnt(0)" ::: "memory");
    __builtin_amdgcn_s_barrier();
    __builtin_amdgcn_sched_barrier(0);
  }

#pragma unroll
  for (int i = 0; i < 2; ++i)
#pragma unroll
    for (int j = 0; j < 4; ++j) {
      const int row = bm + wr + i * 16 + lHi * 4;
      const int col = bn + wc + j * 16 + l15;
#pragma unroll
      for (int rr = 0; rr < 4; ++rr)
        out[((long)z * 1024 + row + rr) * 512 + col] = acc[i][j][rr];
    }
}

// Full-row softmax (fallback path): in-place fp32 + bf16 P copy.
__global__ __launch_bounds__(256) void softmax_rows(
    float* __restrict__ attn, unsigned short* __restrict__ pbf) {
  const long row = blockIdx.x;
  float4* p = reinterpret_cast<float4*>(attn + row * 2048);
  const int tid = threadIdx.x;
  float4 a = p[tid];
  float4 b = p[tid + 256];
  float m = fmaxf(fmaxf(fmaxf(a.x, a.y), fmaxf(a.z, a.w)),
                  fmaxf(fmaxf(b.x, b.y), fmaxf(b.z, b.w)));
#pragma unroll
  for (int o = 32; o; o >>= 1) m = fmaxf(m, __shfl_xor(m, o, 64));
  __shared__ float redm[4];
  if ((tid & 63) == 0) redm[tid >> 6] = m;
  __syncthreads();
  m = fmaxf(fmaxf(redm[0], redm[1]), fmaxf(redm[2], redm[3]));
  float e0 = __expf(a.x - m), e1 = __expf(a.y - m), e2 = __expf(a.z - m), e3 = __expf(a.w - m);
  float e4 = __expf(b.x - m), e5 = __expf(b.y - m), e6 = __expf(b.z - m), e7 = __expf(b.w - m);
  float s = ((e0 + e1) + (e2 + e3)) + ((e4 + e5) + (e6 + e7));
#pragma unroll
  for (int o = 32; o; o >>= 1) s += __shfl_xor(s, o, 64);
  __shared__ float reds[4];
  if ((tid & 63) == 0) reds[tid >> 6] = s;
  __syncthreads();
  s = (reds[0] + reds[1]) + (reds[2] + reds[3]);
  const float inv = 1.0f / s;
  a.x = e0 * inv; a.y = e1 * inv; a.z = e2 * inv; a.w = e3 * inv;
  b.x = e4 * inv; b.y = e5 * inv; b.z = e6 * inv; b.w = e7 * inv;
  p[tid] = a;
  p[tid + 256] = b;
  ushort4 o0, o1;
  o0.x = f2bf(a.x); o0.y = f2bf(a.y); o0.z = f2bf(a.z); o0.w = f2bf(a.w);
  o1.x = f2bf(b.x); o1.y = f2bf(b.y); o1.z = f2bf(b.z); o1.w = f2bf(b.w);
  *reinterpret_cast<ushort4*>(pbf + row * 2048 + tid * 4) = o0;
  *reinterpret_cast<ushort4*>(pbf + row * 2048 + 1024 + tid * 4) = o1;
}

// fp32 -> bf16 for two buffers in one launch, 8 elems/thread, grid-stride.
__global__ __launch_bounds__(256) void f32_to_bf16_2(
    const float* __restrict__ inA, unsigned short* __restrict__ outA, long nA,
    const float* __restrict__ inB, unsigned short* __restrict__ outB, long nB) {
  const long total = nA + nB;
  long i = ((long)blockIdx.x * blockDim.x + threadIdx.x) * 8;
  const long stride = (long)gridDim.x * blockDim.x * 8;
  for (; i < total; i += stride) {
    const float* in = (i < nA) ? inA + i : inB + (i - nA);
    unsigned short* out = (i < nA) ? outA + i : outB + (i - nA);
    const float4 a = *reinterpret_cast<const float4*>(in);
    const float4 b = *reinterpret_cast<const float4*>(in + 4);
    short8v o;
    o[0] = (short)f2bf(a.x); o[1] = (short)f2bf(a.y);
    o[2] = (short)f2bf(a.z); o[3] = (short)f2bf(a.w);
    o[4] = (short)f2bf(b.x); o[5] = (short)f2bf(b.y);
    o[6] = (short)f2bf(b.z); o[7] = (short)f2bf(b.w);
    *reinterpret_cast<short8v*>(out) = o;
  }
}

// Transpose+convert the three 512x512 fp32 weights to bf16 W^T.
__global__ __launch_bounds__(256) void transpose_w3(
    const float* __restrict__ Wq, const float* __restrict__ Wk, const float* __restrict__ Wv,
    unsigned short* __restrict__ WqT, unsigned short* __restrict__ WkT,
    unsigned short* __restrict__ WvT) {
  __shared__ float t[32][33];
  const int zz = blockIdx.z;
  const float* W = zz == 0 ? Wq : zz == 1 ? Wk : Wv;
  unsigned short* WT = zz == 0 ? WqT : zz == 1 ? WkT : WvT;
  const int bx = blockIdx.x * 32;
  const int by = blockIdx.y * 32;
  const int tx = threadIdx.x, ty = threadIdx.y;  // (32,8)
#pragma unroll
  for (int i = 0; i < 4; ++i)
    t[ty + i * 8][tx] = W[(long)(by + ty + i * 8) * 512 + bx + tx];
  __syncthreads();
#pragma unroll
  for (int i = 0; i < 4; ++i)
    WT[(long)(bx + ty + i * 8) * 512 + by + tx] = f2bf(t[tx][ty + i * 8]);
}

// In-place LayerNorm over rows of 512 fp32. One wave per row.
__global__ __launch_bounds__(64) void layernorm_rows(
    float* __restrict__ out, const float* __restrict__ gamma, const float* __restrict__ beta) {
  const long row = blockIdx.x;
  float4* p = reinterpret_cast<float4*>(out + row * 512);
  const int lane = threadIdx.x;
  float4 a = p[lane];
  float4 b = p[lane + 64];
  float s = ((a.x + a.y) + (a.z + a.w)) + ((b.x + b.y) + (b.z + b.w));
  float s2 = ((a.x * a.x + a.y * a.y) + (a.z * a.z + a.w * a.w)) +
             ((b.x * b.x + b.y * b.y) + (b.z * b.z + b.w * b.w));
#pragma unroll
  for (int o = 32; o; o >>= 1) {
    s += __shfl_xor(s, o, 64);
    s2 += __shfl_xor(s2, o, 64);
  }
  const float mean = s * (1.0f / 512.0f);
  const float var = s2 * (1.0f / 512.0f) - mean * mean;
  const float rstd = rsqrtf(var + 1e-5f);
  const float4 g0 = reinterpret_cast<const float4*>(gamma)[lane];
  const float4 g1 = reinterpret_cast<const float4*>(gamma)[lane + 64];
  const float4 c0 = reinterpret_cast<const float4*>(beta)[lane];
  const float4 c1 = reinterpret_cast<const float4*>(beta)[lane + 64];
  a.x = (a.x - mean) * rstd * g0.x + c0.x;
  a.y = (a.y - mean) * rstd * g0.y + c0.y;
  a.z = (a.z - mean) * rstd * g0.z + c0.z;
  a.w = (a.w - mean) * rstd * g0.w + c0.w;
  b.x = (b.x - mean) * rstd * g1.x + c1.x;
  b.y = (b.y - mean) * rstd * g1.y + c1.y;
  b.z = (b.z - mean) * rstd * g1.z + c1.z;
  b.w = (b.w - mean) * rstd * g1.w + c1.w;
  p[lane] = a;
  p[lane + 64] = b;
}

extern "C" void kernel_launch(void* const* d_in, const int* in_sizes, int n_in,
                              void* d_out, int out_size, void* d_ws, size_t ws_size,
                              hipStream_t stream) {
  const float* mel  = (const float*)d_in[0];   // [16,2048,512]
  const float* text = (const float*)d_in[1];   // [16,1024,512]
  const int* melMask = (const int*)d_in[2];    // [16,2048]
  const int* srcMask = (const int*)d_in[3];    // [16,1024]
  const float* Wq = (const float*)d_in[4];
  const float* Wk = (const float*)d_in[5];
  const float* Wv = (const float*)d_in[6];
  const float* gamma = (const float*)d_in[7];
  const float* beta  = (const float*)d_in[8];

  float* out = (float*)d_out;                           // [16,1024,512]
  float* attn = (float*)d_out + (long)16 * 1024 * 512;  // [16,1024,2048]

  unsigned short* ws = (unsigned short*)d_ws;
  unsigned short* wqT = ws;
  unsigned short* wkT = wqT + 512 * 512;
  unsigned short* wvT = wkT + 512 * 512;
  unsigned short* melbf  = wvT + 512 * 512;               // 16*2048*512
  unsigned short* textbf = melbf + (long)16 * 2048 * 512; // 16*1024*512
  unsigned short* qbf = textbf + (long)16 * 1024 * 512;
  unsigned short* kbf = qbf + (long)16 * 1024 * 512;
  unsigned short* vT  = kbf + (long)16 * 2048 * 512;      // 16*512*2048
  unsigned short* sbf = vT + (long)16 * 512 * 2048;       // 16*1024*2048 bf16
  // stats [16][1024][16][2] fp32 aliases melbf (dead after kv GEMM).
  float* stats = (float*)melbf;
  // base buffers = 135,790,592 B; + sbf 67,108,864 B.
  const bool bigws = ws_size >= 202899456ull;

  transpose_w3<<<dim3(16, 16, 3), dim3(32, 8), 0, stream>>>(Wq, Wk, Wv, wqT, wkT, wvT);
  f32_to_bf16_2<<<dim3(6144), 256, 0, stream>>>(
      mel, melbf, (long)16 * 2048 * 512, text, textbf, (long)16 * 1024 * 512);

  // q = text @ Wq (bf16), GM=2: text panels XCD-co-located
  gemm_bf16<128, 0, 2><<<dim3(128, 4, 1), 256, 0, stream>>>(
      textbf, wqT, qbf, 16384, 512, 512, 0, 0, 0, nullptr, nullptr, 1.0f, nullptr);
  // k + vT in one pass over mel
  gemm_kv<<<dim3(1024), 256, 0, stream>>>(melbf, wkT, wvT, kbf, vT);

  if (bigws) {
    // raw masked scores (bf16) + stats, batch->XCD swizzled
    gemm_bf16<128, 2, 1><<<dim3(2048), 256, 0, stream>>>(
        qbf, kbf, sbf, 1024, 2048, 512,
        (long)1024 * 512, (long)2048 * 512, (long)1024 * 2048,
        srcMask, melMask, 0.044194173824159216f, stats);
    // fused softmax(+balanced attn write) + PV, 2-phase pipeline
    pv_smx<<<dim3(1024), 256, 0, stream>>>(sbf, vT, attn, out, stats);
  } else {
    // fallback: fp32 scores in attn region, in-place softmax, PV from pbf
    unsigned short* pbf = melbf;
    gemm_bf16<128, 3, 0><<<dim3(16, 8, 16), 256, 0, stream>>>(
        qbf, kbf, attn, 1024, 2048, 512,
        (long)1024 * 512, (long)2048 * 512, (long)1024 * 2048,
        srcMask, melMask, 0.044194173824159216f, nullptr);
    softmax_rows<<<dim3(16 * 1024), 256, 0, stream>>>(attn, pbf);
    gemm_bf16<64, 1, 0><<<dim3(4, 16, 16), 256, 0, stream>>>(
        pbf, vT, out, 1024, 512, 2048,
        (long)1024 * 2048, (long)512 * 2048, (long)1024 * 512,
        nullptr, nullptr, 1.0f, nullptr);
  }
  layernorm_rows<<<dim3(16 * 1024), 64, 0, stream>>>(out, gamma, beta);
}

// Round 9
// 266.952 us; speedup vs baseline: 1.2607x; 1.2607x over previous
//
#include <hip/hip_runtime.h>

#define DEV __device__ __forceinline__

typedef __attribute__((ext_vector_type(8))) short short8v;
typedef __attribute__((ext_vector_type(4))) float f32x4;

DEV unsigned short f2bf(float f) {
  unsigned int x = __float_as_uint(f);
  x = x + 0x7FFFu + ((x >> 16) & 1u);   // RNE
  return (unsigned short)(x >> 16);
}
DEV float bf2f(unsigned short u) {
  return __uint_as_float(((unsigned)u) << 16);
}

// ---- swizzled LDS tile, BK=64: row stride 128 B, 8x16B chunks (0 confl) ----
DEV int swz_byte(int row, int kElem) {
  int chunk = ((kElem >> 3) ^ (row & 7));
  return row * 128 + (chunk << 4) + ((kElem & 7) << 1);
}

// Stage ROUNDS*32 rows x 64 cols of bf16 (256-thread kernels), BK=64 swizzle.
template <int ROUNDS>
DEV void stage(const unsigned short* __restrict__ g, int ld,
               unsigned short* tile, int tid) {
  const int wave = tid >> 6, l = tid & 63;
#pragma unroll
  for (int p = 0; p < ROUNDS; ++p) {
    const int r = (p << 5) + (wave << 3) + (l >> 3);
    const int c = ((l & 7) ^ (r & 7)) << 3;              // pre-swizzled col
    const unsigned short* src = g + (long)r * ld + c;
#if __has_builtin(__builtin_amdgcn_global_load_lds)
    unsigned short* dst = tile + (p << 11) + (wave << 9);  // wave-uniform
    __builtin_amdgcn_global_load_lds(
        (const __attribute__((address_space(1))) void*)src,
        (__attribute__((address_space(3))) void*)dst, 16, 0, 0);
#else
    short8v v = *reinterpret_cast<const short8v*>(src);
    *reinterpret_cast<short8v*>(reinterpret_cast<char*>(tile) +
                                (p << 12) + (wave << 10) + (l << 4)) = v;
#endif
  }
}

// Reg-staged fp32 -> bf16 A-staging (round-1 validated): BM rows x 64 cols.
template <int BM>
DEV void stage_f32(const float* __restrict__ g, int ld,
                   unsigned short* tile, int tid) {
  const int rl = tid >> 4;           // 0..15
  const int c4 = (tid & 15) << 2;    // 0,4,...,60
#pragma unroll
  for (int p = 0; p < BM / 16; ++p) {
    const int row = (p << 4) + rl;
    const float4 f = *reinterpret_cast<const float4*>(g + (long)row * ld + c4);
    ushort4 pack;
    pack.x = f2bf(f.x); pack.y = f2bf(f.y); pack.z = f2bf(f.z); pack.w = f2bf(f.w);
    *reinterpret_cast<ushort4*>(reinterpret_cast<char*>(tile) +
                                swz_byte(row, c4)) = pack;
  }
}

// NT GEMM: C[M][N] = A[M][K] * B[N][K]^T. Tile BM x 128, BK=64.
// EPI: 0 -> bf16; 1 -> f32; 2 -> masked raw scores BF16 + stats.
// GM : 0: (x=nt, y=mt, z=z); 1: 1-D batch->XCD swizzle (scores);
//      2: (x=mt, y=nt, z=z).
// AF32: A operand is fp32, converted during reg-staging.
template <int BM, int EPI, int GM, bool AF32>
__global__ __launch_bounds__(256) void gemm_bf16(
    const void* __restrict__ Av, const unsigned short* __restrict__ B,
    void* __restrict__ Cout, int M, int N, int K,
    long aBatch, long bBatch, long cBatch,
    const int* __restrict__ srcMask, const int* __restrict__ melMask,
    float scale, float* __restrict__ stats) {
  constexpr int NI = BM / 32;
  __shared__ unsigned short As[BM * 64];
  __shared__ unsigned short Bs[128 * 64];
  const int tid = threadIdx.x;
  const int lane = tid & 63;
  const int wave = tid >> 6;
  int z, bmi, bni;
  if constexpr (GM == 1) {
    const int id = blockIdx.x;            // 16z x 16nt x 8mt = 2048
    z = (id & 7) | ((id >> 10) << 3);
    const int ib = (id >> 3) & 127;
    bni = ib & 15;
    bmi = ib >> 4;
  } else if constexpr (GM == 2) {
    bmi = blockIdx.x; bni = blockIdx.y; z = blockIdx.z;
  } else {
    bni = blockIdx.x; bmi = blockIdx.y; z = blockIdx.z;
  }
  const int bm = bmi * BM;
  const int bn = bni * 128;
  const unsigned short* Bb = B + (long)z * bBatch;
  const long cOff = (long)z * cBatch;
  const int wr = (wave >> 1) * (BM / 2);
  const int wc = (wave & 1) * 64;
  const int l15 = lane & 15;
  const int lHi = lane >> 4;

  f32x4 acc[NI][4] = {};

  for (int kt = 0; kt < K; kt += 64) {
    if constexpr (AF32) {
      stage_f32<BM>((const float*)Av + (long)z * aBatch + (long)bm * K + kt, K, As, tid);
    } else {
      stage<BM / 32>((const unsigned short*)Av + (long)z * aBatch + (long)bm * K + kt,
                     K, As, tid);
    }
    stage<4>(Bb + (long)bn * K + kt, K, Bs, tid);
    __syncthreads();
#pragma unroll
    for (int ks = 0; ks < 2; ++ks) {
      const int k0 = (ks << 5) + (lHi << 3);
      short8v af[NI], bfr[4];
#pragma unroll
      for (int i = 0; i < NI; ++i)
        af[i] = *reinterpret_cast<const short8v*>(
            reinterpret_cast<const char*>(As) + swz_byte(wr + i * 16 + l15, k0));
#pragma unroll
      for (int j = 0; j < 4; ++j)
        bfr[j] = *reinterpret_cast<const short8v*>(
            reinterpret_cast<const char*>(Bs) + swz_byte(wc + j * 16 + l15, k0));
#pragma unroll
      for (int i = 0; i < NI; ++i)
#pragma unroll
        for (int j = 0; j < 4; ++j)
          acc[i][j] = __builtin_amdgcn_mfma_f32_16x16x32_bf16(af[i], bfr[j], acc[i][j], 0, 0, 0);
    }
    __syncthreads();
  }

  if constexpr (EPI == 2) {
    __shared__ float redM[128][2];
    __shared__ float redS[128][2];
    const int wcIdx = wave & 1;
#pragma unroll
    for (int i = 0; i < NI; ++i) {
#pragma unroll
      for (int rr = 0; rr < 4; ++rr) {
        const int rloc = wr + i * 16 + lHi * 4 + rr;
        const int rb = bm + rloc;
        const bool sm = srcMask[z * 1024 + rb] != 0;
        float vals[4];
        float m_l = -3.0e38f;
#pragma unroll
        for (int j = 0; j < 4; ++j) {
          const int c = bn + wc + j * 16 + l15;
          const bool mm = melMask[z * 2048 + c] != 0;
          const float vf = (sm && mm) ? -1e30f : acc[i][j][rr] * scale;
          vals[j] = vf;
          reinterpret_cast<unsigned short*>(Cout)[cOff + (long)rb * N + c] = f2bf(vf);
          m_l = fmaxf(m_l, vf);
        }
#pragma unroll
        for (int o = 1; o < 16; o <<= 1) m_l = fmaxf(m_l, __shfl_xor(m_l, o, 64));
        float s_l = 0.f;
#pragma unroll
        for (int j = 0; j < 4; ++j) s_l += __expf(vals[j] - m_l);
#pragma unroll
        for (int o = 1; o < 16; o <<= 1) s_l += __shfl_xor(s_l, o, 64);
        if (l15 == 0) { redM[rloc][wcIdx] = m_l; redS[rloc][wcIdx] = s_l; }
      }
    }
    __syncthreads();
    if (tid < 128) {
      const float m0 = redM[tid][0], m1 = redM[tid][1];
      const float Mx = fmaxf(m0, m1);
      const float S = redS[tid][0] * __expf(m0 - Mx) + redS[tid][1] * __expf(m1 - Mx);
      const long sidx = ((long)(z * 1024 + bm + tid)) * 32 + (long)bni * 2;
      stats[sidx] = Mx;
      stats[sidx + 1] = S;
    }
  } else {
#pragma unroll
    for (int i = 0; i < NI; ++i) {
#pragma unroll
      for (int j = 0; j < 4; ++j) {
        const int rb = bm + wr + i * 16 + lHi * 4;
        const int c = bn + wc + j * 16 + l15;
#pragma unroll
        for (int r = 0; r < 4; ++r) {
          const float v = acc[i][j][r];
          const long idx = cOff + (long)(rb + r) * N + c;
          if constexpr (EPI == 0)
            reinterpret_cast<unsigned short*>(Cout)[idx] = f2bf(v);
          else
            reinterpret_cast<float*>(Cout)[idx] = v;
        }
      }
    }
  }
}

// Fused softmax + PV (round-7 proven 2-barrier body, BM=32 for max TLP).
// BM=32 q-rows x BN=128 out-cols, BK=64, 256 thr, 7 blocks/CU.
// Block nt writes normalized attn fp32 for kt in [nt*512,(nt+1)*512).
// 1-D grid 2048 (16z x 32mt x 4nt), batch->XCD co-located.
__global__ __launch_bounds__(256) void pv_smx(
    const unsigned short* __restrict__ sbf, const unsigned short* __restrict__ vT,
    float* __restrict__ attn, float* __restrict__ out,
    const float* __restrict__ stats) {
  __shared__ unsigned short As[32 * 64];     // 4 KB
  __shared__ unsigned short Bs[128 * 64];    // 16 KB
  __shared__ float rowM[32], rowInv[32];
  const int id = blockIdx.x;
  const int z = (id & 7) | ((id >> 10) << 3);
  const int ib = (id >> 3) & 127;
  const int mt = ib & 31, nt = ib >> 5;
  const int bm = mt * 32, bn = nt * 128;
  const int tid = threadIdx.x, lane = tid & 63, wave = tid >> 6;

  if (tid < 32) {
    const float* st = stats + ((long)(z * 1024 + bm + tid)) * 32;
    float Mx = -3.0e38f;
#pragma unroll
    for (int t = 0; t < 16; ++t) Mx = fmaxf(Mx, st[t * 2]);
    float S = 0.f;
#pragma unroll
    for (int t = 0; t < 16; ++t) S += st[t * 2 + 1] * __expf(st[t * 2] - Mx);
    rowM[tid] = Mx;
    rowInv[tid] = 1.0f / S;
  }
  __syncthreads();

  const int ar = tid >> 3;               // A row 0..31 (8 thr/row)
  const int ac = (tid & 7) << 3;         // 8 elems per thread
  const float mR = rowM[ar];
  const float invR = rowInv[ar];
  const long aOff = ((long)z * 1024 + bm + ar) * 2048 + ac;
  const unsigned short* vTb = vT + ((long)z * 512 + bn) * 2048;
  const int wr = (wave >> 1) * 16, wc = (wave & 1) * 64;
  const int l15 = lane & 15, lHi = lane >> 4;

  f32x4 acc[4] = {};

  for (int kt = 0; kt < 2048; kt += 64) {
    stage<4>(vTb + kt, 2048, Bs, tid);     // B: async global->LDS
    // A: 8 raw bf16 scores -> exp-normalize -> bf16 LDS (+ attn if owner)
    const short8v s0 = *reinterpret_cast<const short8v*>(sbf + aOff + kt);
    float e[8];
#pragma unroll
    for (int u = 0; u < 8; ++u)
      e[u] = __expf(bf2f((unsigned short)s0[u]) - mR) * invR;
    if ((kt >> 9) == nt) {                 // balanced exactly-once attn write
      float* ap = attn + aOff + kt;
      float4 w0, w1;
      w0.x = e[0]; w0.y = e[1]; w0.z = e[2]; w0.w = e[3];
      w1.x = e[4]; w1.y = e[5]; w1.z = e[6]; w1.w = e[7];
      *reinterpret_cast<float4*>(ap) = w0;
      *reinterpret_cast<float4*>(ap + 4) = w1;
    }
    short8v pk;
#pragma unroll
    for (int u = 0; u < 8; ++u) pk[u] = (short)f2bf(e[u]);
    *reinterpret_cast<short8v*>(reinterpret_cast<char*>(As) + swz_byte(ar, ac)) = pk;
    __syncthreads();

#pragma unroll
    for (int ks = 0; ks < 2; ++ks) {
      const int k0 = (ks << 5) + (lHi << 3);
      short8v af, bfr[4];
      af = *reinterpret_cast<const short8v*>(
          reinterpret_cast<const char*>(As) + swz_byte(wr + l15, k0));
#pragma unroll
      for (int j = 0; j < 4; ++j)
        bfr[j] = *reinterpret_cast<const short8v*>(
            reinterpret_cast<const char*>(Bs) + swz_byte(wc + j * 16 + l15, k0));
#pragma unroll
      for (int j = 0; j < 4; ++j)
        acc[j] = __builtin_amdgcn_mfma_f32_16x16x32_bf16(af, bfr[j], acc[j], 0, 0, 0);
    }
    __syncthreads();
  }

#pragma unroll
  for (int j = 0; j < 4; ++j) {
    const int row = bm + wr + lHi * 4;
    const int col = bn + wc + j * 16 + l15;
#pragma unroll
    for (int rr = 0; rr < 4; ++rr)
      out[((long)z * 1024 + row + rr) * 512 + col] = acc[j][rr];
  }
}

// fp32 -> bf16 elementwise, 8 elems/thread, grid-stride.
__global__ __launch_bounds__(256) void f32_to_bf16(
    const float* __restrict__ in, unsigned short* __restrict__ out, long n) {
  long i = ((long)blockIdx.x * blockDim.x + threadIdx.x) * 8;
  const long stride = (long)gridDim.x * blockDim.x * 8;
  for (; i < n; i += stride) {
    const float4 a = *reinterpret_cast<const float4*>(in + i);
    const float4 b = *reinterpret_cast<const float4*>(in + i + 4);
    short8v o;
    o[0] = (short)f2bf(a.x); o[1] = (short)f2bf(a.y);
    o[2] = (short)f2bf(a.z); o[3] = (short)f2bf(a.w);
    o[4] = (short)f2bf(b.x); o[5] = (short)f2bf(b.y);
    o[6] = (short)f2bf(b.z); o[7] = (short)f2bf(b.w);
    *reinterpret_cast<short8v*>(out + i) = o;
  }
}

// Convert Wq and Wk (512x512 fp32) to bf16, no transpose. Grid (128, 2).
__global__ __launch_bounds__(256) void conv_w2(
    const float* __restrict__ Wq, const float* __restrict__ Wk,
    unsigned short* __restrict__ wqbf, unsigned short* __restrict__ wkbf) {
  const float* in = blockIdx.y ? Wk : Wq;
  unsigned short* out = blockIdx.y ? wkbf : wqbf;
  const long i = ((long)blockIdx.x * 256 + threadIdx.x) * 8;
  const float4 a = *reinterpret_cast<const float4*>(in + i);
  const float4 b = *reinterpret_cast<const float4*>(in + i + 4);
  short8v o;
  o[0] = (short)f2bf(a.x); o[1] = (short)f2bf(a.y);
  o[2] = (short)f2bf(a.z); o[3] = (short)f2bf(a.w);
  o[4] = (short)f2bf(b.x); o[5] = (short)f2bf(b.y);
  o[6] = (short)f2bf(b.z); o[7] = (short)f2bf(b.w);
  *reinterpret_cast<short8v*>(out + i) = o;
}

// Transpose+convert Wv (512x512 fp32) to bf16 Wv^T. Grid (16,16), block (32,8).
__global__ __launch_bounds__(256) void transpose_wv(
    const float* __restrict__ Wv, unsigned short* __restrict__ WvT) {
  __shared__ float t[32][33];
  const int bx = blockIdx.x * 32;
  const int by = blockIdx.y * 32;
  const int tx = threadIdx.x, ty = threadIdx.y;
#pragma unroll
  for (int i = 0; i < 4; ++i)
    t[ty + i * 8][tx] = Wv[(long)(by + ty + i * 8) * 512 + bx + tx];
  __syncthreads();
#pragma unroll
  for (int i = 0; i < 4; ++i)
    WvT[(long)(bx + ty + i * 8) * 512 + by + tx] = f2bf(t[tx][ty + i * 8]);
}

// In-place LayerNorm over rows of 512 fp32. One wave per row.
__global__ __launch_bounds__(64) void layernorm_rows(
    float* __restrict__ out, const float* __restrict__ gamma, const float* __restrict__ beta) {
  const long row = blockIdx.x;
  float4* p = reinterpret_cast<float4*>(out + row * 512);
  const int lane = threadIdx.x;
  float4 a = p[lane];
  float4 b = p[lane + 64];
  float s = ((a.x + a.y) + (a.z + a.w)) + ((b.x + b.y) + (b.z + b.w));
  float s2 = ((a.x * a.x + a.y * a.y) + (a.z * a.z + a.w * a.w)) +
             ((b.x * b.x + b.y * b.y) + (b.z * b.z + b.w * b.w));
#pragma unroll
  for (int o = 32; o; o >>= 1) {
    s += __shfl_xor(s, o, 64);
    s2 += __shfl_xor(s2, o, 64);
  }
  const float mean = s * (1.0f / 512.0f);
  const float var = s2 * (1.0f / 512.0f) - mean * mean;
  const float rstd = rsqrtf(var + 1e-5f);
  const float4 g0 = reinterpret_cast<const float4*>(gamma)[lane];
  const float4 g1 = reinterpret_cast<const float4*>(gamma)[lane + 64];
  const float4 c0 = reinterpret_cast<const float4*>(beta)[lane];
  const float4 c1 = reinterpret_cast<const float4*>(beta)[lane + 64];
  a.x = (a.x - mean) * rstd * g0.x + c0.x;
  a.y = (a.y - mean) * rstd * g0.y + c0.y;
  a.z = (a.z - mean) * rstd * g0.z + c0.z;
  a.w = (a.w - mean) * rstd * g0.w + c0.w;
  b.x = (b.x - mean) * rstd * g1.x + c1.x;
  b.y = (b.y - mean) * rstd * g1.y + c1.y;
  b.z = (b.z - mean) * rstd * g1.z + c1.z;
  b.w = (b.w - mean) * rstd * g1.w + c1.w;
  p[lane] = a;
  p[lane + 64] = b;
}

extern "C" void kernel_launch(void* const* d_in, const int* in_sizes, int n_in,
                              void* d_out, int out_size, void* d_ws, size_t ws_size,
                              hipStream_t stream) {
  const float* mel  = (const float*)d_in[0];   // [16,2048,512]
  const float* text = (const float*)d_in[1];   // [16,1024,512]
  const int* melMask = (const int*)d_in[2];    // [16,2048]
  const int* srcMask = (const int*)d_in[3];    // [16,1024]
  const float* Wq = (const float*)d_in[4];
  const float* Wk = (const float*)d_in[5];
  const float* Wv = (const float*)d_in[6];
  const float* gamma = (const float*)d_in[7];
  const float* beta  = (const float*)d_in[8];

  float* out = (float*)d_out;                           // [16,1024,512]
  float* attn = (float*)d_out + (long)16 * 1024 * 512;  // [16,1024,2048]

  unsigned short* ws = (unsigned short*)d_ws;
  unsigned short* wqbf = ws;                              // 512*512
  unsigned short* wkbf = wqbf + 512 * 512;
  unsigned short* wvT  = wkbf + 512 * 512;
  unsigned short* Mt   = wvT + 512 * 512;                 // (Wq Wk^T)^T bf16
  unsigned short* melbf = Mt + 512 * 512;                 // 16*2048*512
  unsigned short* qbf  = melbf + (long)16 * 2048 * 512;   // 16*1024*512
  unsigned short* vT   = qbf + (long)16 * 1024 * 512;     // 16*512*2048
  unsigned short* sbf  = vT + (long)16 * 512 * 2048;      // 16*1024*2048
  float* stats = (float*)(sbf + (long)16 * 1024 * 2048);  // 16*1024*16*2 f32
  // total: 2 MB + 33.5 + 16.8 + 33.5 + 67.1 + 2 = ~155 MB (< ws_size)

  // weight prep
  conv_w2<<<dim3(128, 2), 256, 0, stream>>>(Wq, Wk, wqbf, wkbf);
  transpose_wv<<<dim3(16, 16), dim3(32, 8), 0, stream>>>(Wv, wvT);
  f32_to_bf16<<<dim3(4096), 256, 0, stream>>>(mel, melbf, (long)16 * 2048 * 512);

  // Mt[e][d] = sum_m Wk[e][m]*Wq[d][m]  == (Wq Wk^T)^T
  gemm_bf16<128, 0, 0, false><<<dim3(4, 4, 1), 256, 0, stream>>>(
      wkbf, wqbf, Mt, 512, 512, 512, 0, 0, 0, nullptr, nullptr, 1.0f, nullptr);
  // q' = text @ Mt^T (fp32 A converted in staging)
  gemm_bf16<128, 0, 2, true><<<dim3(128, 4, 1), 256, 0, stream>>>(
      text, Mt, qbf, 16384, 512, 512, 0, 0, 0, nullptr, nullptr, 1.0f, nullptr);
  // vT[m][s] = sum_d WvT[m][d]*mel[s][d]
  gemm_bf16<128, 0, 0, false><<<dim3(16, 4, 16), 256, 0, stream>>>(
      wvT, melbf, vT, 512, 2048, 512, 0, (long)2048 * 512, (long)512 * 2048,
      nullptr, nullptr, 1.0f, nullptr);
  // raw masked scores (bf16) + stats; B = melbf directly (k folded into q')
  gemm_bf16<128, 2, 1, false><<<dim3(2048), 256, 0, stream>>>(
      qbf, melbf, sbf, 1024, 2048, 512,
      (long)1024 * 512, (long)2048 * 512, (long)1024 * 2048,
      srcMask, melMask, 0.044194173824159216f, stats);
  // fused softmax(+balanced attn write) + PV, high-TLP config
  pv_smx<<<dim3(2048), 256, 0, stream>>>(sbf, vT, attn, out, stats);
  layernorm_rows<<<dim3(16 * 1024), 64, 0, stream>>>(out, gamma, beta);
}